// Round 1
// 468.687 us; speedup vs baseline: 1.0269x; 1.0269x over previous
//
#include <hip/hip_runtime.h>

typedef _Float16 h8v __attribute__((ext_vector_type(8)));
typedef _Float16 h4v __attribute__((ext_vector_type(4)));
typedef float    f4v __attribute__((ext_vector_type(4)));

#define MFMA16(a,b,c) __builtin_amdgcn_mfma_f32_16x16x32_f16((a),(b),(c),0,0,0)
#define NEGF (-1e30f)

#define MEM 1000
#define KEY 64
#define VAL 128
#define DIN 512
#define BS  512
#define BQ  65536

// Fragment-major B layouts: element (F,KS,lane,j) at ((F*nKS+KS)*64+lane)*8+j
// holds B[n = F*16 + (lane&15)][k = KS*32 + (lane>>4)*8 + j]  -> every MFMA
// B-fragment load is lane-contiguous (16 B/lane, 1 KB/wave, 8 full lines).
// qfpq is A-fragment-major: tile t (16 queries), frag KS in 0..3 (k=KS*32..):
// offset ((t*4+KS)*64+lane)*8 ; KS 0,1 = qf cols, KS 2,3 = pq cols.

__device__ __forceinline__ h8v cvt8(const float* p)
{
  f4v u = *(const f4v*)p;
  f4v v = *(const f4v*)(p + 4);
  h8v a;
  a[0] = (_Float16)u.x; a[1] = (_Float16)u.y; a[2] = (_Float16)u.z; a[3] = (_Float16)u.w;
  a[4] = (_Float16)v.x; a[5] = (_Float16)v.y; a[6] = (_Float16)v.z; a[7] = (_Float16)v.w;
  return a;
}

__device__ __forceinline__ h8v cvt8nt(const float* p)
{
  f4v u = __builtin_nontemporal_load((const f4v*)p);
  f4v v = __builtin_nontemporal_load((const f4v*)(p + 4));
  h8v a;
  a[0] = (_Float16)u.x; a[1] = (_Float16)u.y; a[2] = (_Float16)u.z; a[3] = (_Float16)u.w;
  a[4] = (_Float16)v.x; a[5] = (_Float16)v.y; a[6] = (_Float16)v.z; a[7] = (_Float16)v.w;
  return a;
}

// ---------------------------------------------------------------------------
// prep1: fragment-major weights, Wck = baseW@kpW fused, bcomb, ranks, zero
// ---------------------------------------------------------------------------
__global__ void k_prep1(const float* __restrict__ baseW, const float* __restrict__ base_b,
                        const float* __restrict__ kpW, const float* __restrict__ kp_b,
                        const float* __restrict__ vpW, const float* __restrict__ c1W,
                        const float* __restrict__ c2W, const float* __restrict__ age,
                        _Float16* __restrict__ WTf, float* __restrict__ bcomb,
                        _Float16* __restrict__ vpWt, _Float16* __restrict__ c1F,
                        _Float16* __restrict__ c2F, int* __restrict__ ranks,
                        float* __restrict__ out0)
{
  long id = (long)blockIdx.x * 256 + threadIdx.x;
  if (id < 65536) {                        // WTf: [baseW^T | Wck^T], n=128, k=512 (KS=16)
    int h = (int)id;
    int j = h & 7, lane = (h >> 3) & 63, KS = (h >> 9) & 15, F = h >> 13;
    int n = F * 16 + (lane & 15);
    int k = KS * 32 + ((lane >> 4) << 3) + j;
    float v;
    if (n < 64) v = baseW[(size_t)k * 64 + n];
    else {
      int nn = n - 64;
      const float* br = baseW + (size_t)k * 64;
      float s = 0.f;
      for (int t = 0; t < 64; ++t) s += br[t] * kpW[t * 64 + nn];
      v = s;
    }
    WTf[h] = (_Float16)v;
  } else if (id < 65664) {                 // bcomb
    int i = (int)(id - 65536);
    if (i < 64) bcomb[i] = base_b[i];
    else {
      int n = i - 64;
      float s = kp_b[n];
      for (int t = 0; t < 64; ++t) s += base_b[t] * kpW[t * 64 + n];
      bcomb[i] = s;
    }
  } else if (id < 90240) {                 // c1F: n=128 (F=8), k=192 (KS=6)
    int h = (int)(id - 65664);
    int j = h & 7, lane = (h >> 3) & 63, KS = (h >> 9) % 6, F = (h >> 9) / 6;
    int n = F * 16 + (lane & 15);
    int k = KS * 32 + ((lane >> 4) << 3) + j;
    c1F[h] = (_Float16)c1W[(size_t)k * 128 + n];
  } else if (id < 98432) {                 // c2F: n=64 (F=4), k=128 (KS=4)
    int h = (int)(id - 90240);
    int j = h & 7, lane = (h >> 3) & 63, KS = (h >> 9) & 3, F = h >> 11;
    int n = F * 16 + (lane & 15);
    int k = KS * 32 + ((lane >> 4) << 3) + j;
    c2F[h] = (_Float16)c2W[(size_t)k * 64 + n];
  } else if (id < 114816) {                // vpWt[n][k] (row-major transposed, prep2 only)
    long i = id - 98432;
    int n = (int)(i >> 7), k = (int)(i & 127);
    vpWt[i] = (_Float16)vpW[(size_t)k * 128 + n];
  } else if (id < 115816) {                // stable ranks (lax.top_k order)
    int jx = (int)(id - 114816);
    float aj = age[jx];
    int r = 0;
    for (int i2 = 0; i2 < MEM; ++i2) {
      float ai = age[i2];
      r += (ai > aj) || (ai == aj && i2 < jx);
    }
    ranks[jx] = r;
  } else if (id == 115816) {
    *out0 = 0.f;
  }
}

// ---------------------------------------------------------------------------
// prep2: pkeys = sx@Wck + bck ; pvals = sy@vpW + vp_b
// ---------------------------------------------------------------------------
__global__ __launch_bounds__(64) void k_prep2(
    const float* __restrict__ sx, const float* __restrict__ sy,
    const _Float16* __restrict__ WTf, const float* __restrict__ bcomb,
    const _Float16* __restrict__ vpWt, const float* __restrict__ vp_b,
    float* __restrict__ pkeys, float* __restrict__ pvals)
{
  const int lane = threadIdx.x, quad = lane >> 4, l15 = lane & 15;
  const f4v fz = {0.f, 0.f, 0.f, 0.f};
  if (blockIdx.x < 32) {
    const int m0 = blockIdx.x * 16;
    f4v acc[4];
    #pragma unroll
    for (int f = 0; f < 4; ++f) acc[f] = fz;
    const float* xr = sx + (size_t)(m0 + l15) * DIN;
    #pragma unroll 4
    for (int ks = 0; ks < 16; ++ks) {
      int k0 = ks * 32 + quad * 8;
      h8v a = cvt8(xr + k0);
      #pragma unroll
      for (int f = 0; f < 4; ++f) {
        h8v b = *(const h8v*)(WTf + (size_t)((((4 + f) * 16) + ks) * 64 + lane) * 8);
        acc[f] = MFMA16(a, b, acc[f]);
      }
    }
    #pragma unroll
    for (int f = 0; f < 4; ++f) {
      int col = f * 16 + l15;
      float bb = bcomb[64 + col];
      #pragma unroll
      for (int r = 0; r < 4; ++r)
        pkeys[(size_t)(m0 + quad * 4 + r) * KEY + col] = acc[f][r] + bb;
    }
  } else {
    const int m0 = (blockIdx.x - 32) * 16;
    f4v acc[8];
    #pragma unroll
    for (int f = 0; f < 8; ++f) acc[f] = fz;
    const float* yr = sy + (size_t)(m0 + l15) * VAL;
    #pragma unroll
    for (int ks = 0; ks < 4; ++ks) {
      int k0 = ks * 32 + quad * 8;
      h8v a = cvt8(yr + k0);
      #pragma unroll
      for (int f = 0; f < 8; ++f) {
        h8v b = *(const h8v*)(vpWt + (size_t)(f * 16 + l15) * 128 + k0);
        acc[f] = MFMA16(a, b, acc[f]);
      }
    }
    #pragma unroll
    for (int f = 0; f < 8; ++f) {
      int col = f * 16 + l15;
      float bb = vp_b[col];
      #pragma unroll
      for (int r = 0; r < 4; ++r)
        pvals[(size_t)(m0 + quad * 4 + r) * VAL + col] = acc[f][r] + bb;
    }
  }
}

// ---------------------------------------------------------------------------
// prep3: scatter memory into fragment-major keysF / valF (zero-padded)
// keysF: n=1024 slots (F=64), k=KEY 64 (KS=2)
// valF : n=VAL 128 (F=8),     k=1024 slots (KS=32)
// ---------------------------------------------------------------------------
__global__ void k_prep3(const int* __restrict__ ranks, const float* __restrict__ pk,
                        const float* __restrict__ pv, const float* __restrict__ memK,
                        const float* __restrict__ memV,
                        _Float16* __restrict__ keysF, _Float16* __restrict__ valF)
{
  int id = blockIdx.x * 256 + threadIdx.x;
  if (id < 65536) {
    int j = id & 7, lane = (id >> 3) & 63, KS = (id >> 9) & 1, F = id >> 10;
    int n = F * 16 + (lane & 15);                  // mem slot
    int k = KS * 32 + ((lane >> 4) << 3) + j;      // key col
    float v = 0.f;
    if (n < MEM) {
      int rk = ranks[n];
      v = (rk < BS) ? pk[(size_t)rk * KEY + k] : memK[(size_t)n * KEY + k];
    }
    keysF[id] = (_Float16)v;
  } else {
    int h = id - 65536;
    int j = h & 7, lane = (h >> 3) & 63, KS = (h >> 9) & 31, F = h >> 14;
    int nv = F * 16 + (lane & 15);                 // val col
    int jm = KS * 32 + ((lane >> 4) << 3) + j;     // mem slot
    float v = 0.f;
    if (jm < MEM) {
      int rk = ranks[jm];
      v = (rk < BS) ? pv[(size_t)rk * VAL + nv] : memV[(size_t)jm * VAL + nv];
    }
    valF[h] = (_Float16)v;
  }
}

// ---------------------------------------------------------------------------
// feat: qfpq (A-frag-major) = qx @ [baseW | Wck] + bcomb. 16 rows/wave,
// grid 4096 -> 16 waves/CU. nt loads (read-once qx), nt stores.
// ---------------------------------------------------------------------------
__global__ __launch_bounds__(64, 4) void k_feat(const float* __restrict__ qx,
                                                const _Float16* __restrict__ WTf,
                                                const float* __restrict__ bcomb,
                                                _Float16* __restrict__ qfpq)
{
  __shared__ __align__(16) _Float16 tbuf[16 * 136];
  const int lane = threadIdx.x, quad = lane >> 4, l15 = lane & 15;
  const int q0 = blockIdx.x * 16;
  const f4v fz = {0.f, 0.f, 0.f, 0.f};
  f4v acc[8];
  #pragma unroll
  for (int f = 0; f < 8; ++f) acc[f] = fz;

  const float* xr = qx + (size_t)(q0 + l15) * DIN;

  #pragma unroll 4
  for (int ks = 0; ks < 16; ++ks) {
    const int k0 = ks * 32 + quad * 8;
    h8v a = cvt8nt(xr + k0);
    #pragma unroll
    for (int f = 0; f < 8; ++f) {
      h8v b = *(const h8v*)(WTf + (size_t)((f * 16 + ks) * 64 + lane) * 8);
      acc[f] = MFMA16(a, b, acc[f]);
    }
  }
  // C-layout -> LDS -> A-frag-major contiguous nt stores
  #pragma unroll
  for (int f = 0; f < 8; ++f) {
    float bb = bcomb[f * 16 + l15];
    #pragma unroll
    for (int r = 0; r < 4; ++r)
      tbuf[(quad * 4 + r) * 136 + f * 16 + l15] = (_Float16)(acc[f][r] + bb);
  }
  const size_t ob = (size_t)blockIdx.x * 4 * 512;
  #pragma unroll
  for (int KS = 0; KS < 4; ++KS) {
    h8v v = *(const h8v*)&tbuf[l15 * 136 + KS * 32 + quad * 8];
    __builtin_nontemporal_store(v, (h8v*)(qfpq + ob + KS * 512 + lane * 8));
  }
}

// ---------------------------------------------------------------------------
// main: fused attention + controller. 16 queries/wave, grid 4096.
// Chunk-pair ILP (S0/S1), per-lane softmax partial sums (one reduce at end),
// contiguous nt out_ret stores from LDS.
// launch_bounds(64,3): ~170-reg cap. (64,4)'s 128-reg cap forced ~40-60 regs
// of scratch spill per wave in the cc loop (S0/S1=64 acc + O=32 acc + pq + temps
// ~= 165-190 live) -> ~250 MB phantom HBM write + ~120 MB fetch per dispatch.
// 3 waves/SIMD is what the (64,4) build actually achieved anyway (occ 40%).
// ---------------------------------------------------------------------------
__global__ __launch_bounds__(64, 3) void k_main(
    const _Float16* __restrict__ qfpq, const float* __restrict__ qy,
    const float* __restrict__ c1_b, const float* __restrict__ c2_b,
    const float* __restrict__ c3W, const float* __restrict__ c3b,
    const _Float16* __restrict__ c1F, const _Float16* __restrict__ c2F,
    const _Float16* __restrict__ keysF, const _Float16* __restrict__ valF,
    float* __restrict__ dout)
{
  __shared__ __align__(16) char smem[6656];
  _Float16* P_s  = (_Float16*)smem;            // 16 x 136 : P / ret / h1 overlay
  _Float16* h2_s = (_Float16*)(smem + 4352);   // 16 x 72

  const int lane = threadIdx.x;
  const int quad = lane >> 4;
  const int l15  = lane & 15;
  const int q0   = blockIdx.x * 16;

  float* out_pred = dout + 1;
  float* out_ret  = dout + 1 + BQ;
  const f4v fz = {0.f, 0.f, 0.f, 0.f};

  const size_t fb = (size_t)blockIdx.x * 4 * 512;  // A-frag base (halves)
  h8v pq0 = __builtin_nontemporal_load((const h8v*)(qfpq + fb + 2 * 512 + lane * 8));
  h8v pq1 = __builtin_nontemporal_load((const h8v*)(qfpq + fb + 3 * 512 + lane * 8));

  // ---- attention: online softmax, chunk pairs for ILP ----
  float rm[4], rl[4];
  #pragma unroll
  for (int r = 0; r < 4; ++r) { rm[r] = NEGF; rl[r] = 0.f; }
  f4v O[8];
  #pragma unroll
  for (int v = 0; v < 8; ++v) O[v] = fz;

  #pragma unroll 1
  for (int cc = 0; cc < 4; ++cc) {
    const int c0 = cc * 2;
    f4v S0[8], S1[8];
    #pragma unroll
    for (int f = 0; f < 8; ++f) { S0[f] = fz; S1[f] = fz; }

    // QK for both chunks up front (32 independent MFMAs)
    #pragma unroll
    for (int f = 0; f < 8; ++f) {
      const int F = c0 * 8 + f;
      h8v b0 = *(const h8v*)(keysF + (size_t)(F * 2 + 0) * 512 + lane * 8);
      h8v b1 = *(const h8v*)(keysF + (size_t)(F * 2 + 1) * 512 + lane * 8);
      S0[f] = MFMA16(pq0, b0, S0[f]);
      S0[f] = MFMA16(pq1, b1, S0[f]);
    }
    #pragma unroll
    for (int f = 0; f < 8; ++f) {
      const int F = (c0 + 1) * 8 + f;
      h8v b0 = *(const h8v*)(keysF + (size_t)(F * 2 + 0) * 512 + lane * 8);
      h8v b1 = *(const h8v*)(keysF + (size_t)(F * 2 + 1) * 512 + lane * 8);
      S1[f] = MFMA16(pq0, b0, S1[f]);
      S1[f] = MFMA16(pq1, b1, S1[f]);
    }

    #pragma unroll
    for (int par = 0; par < 2; ++par) {
      f4v* S = par ? S1 : S0;
      const int c = c0 + par;

      float cm[4] = {NEGF, NEGF, NEGF, NEGF};
      #pragma unroll
      for (int f = 0; f < 8; ++f) {
        const int col = c * 128 + f * 16 + l15;
        const bool ok = (col < MEM);
        #pragma unroll
        for (int r = 0; r < 4; ++r) {
          float s = ok ? S[f][r] : NEGF;
          S[f][r] = s;
          cm[r] = fmaxf(cm[r], s);
        }
      }
      #pragma unroll
      for (int r = 0; r < 4; ++r) {
        #pragma unroll
        for (int m = 1; m < 16; m <<= 1) cm[r] = fmaxf(cm[r], __shfl_xor(cm[r], m));
      }
      float al[4];
      #pragma unroll
      for (int r = 0; r < 4; ++r) {
        float mn = fmaxf(rm[r], cm[r]);
        al[r] = __expf(rm[r] - mn);
        rm[r] = mn;
      }
      float psl[4] = {0.f, 0.f, 0.f, 0.f};     // per-lane partial sum (no reduce)
      #pragma unroll
      for (int f = 0; f < 8; ++f)
        #pragma unroll
        for (int r = 0; r < 4; ++r) {
          float p = __expf(S[f][r] - rm[r]);
          S[f][r] = p;
          psl[r] += p;
        }
      #pragma unroll
      for (int r = 0; r < 4; ++r) rl[r] = rl[r] * al[r] + psl[r];

      // P -> LDS (C-layout -> A-layout), rescale O, P @ V
      #pragma unroll
      for (int f = 0; f < 8; ++f)
        #pragma unroll
        for (int r = 0; r < 4; ++r)
          P_s[(quad * 4 + r) * 136 + f * 16 + l15] = (_Float16)S[f][r];
      #pragma unroll
      for (int v = 0; v < 8; ++v)
        #pragma unroll
        for (int r = 0; r < 4; ++r) O[v][r] *= al[r];
      #pragma unroll
      for (int ks = 0; ks < 4; ++ks) {
        h8v a = *(const h8v*)&P_s[l15 * 136 + ks * 32 + quad * 8];
        #pragma unroll
        for (int v = 0; v < 8; ++v) {
          h8v b = *(const h8v*)(valF + (size_t)(v * 32 + c * 4 + ks) * 512 + lane * 8);
          O[v] = MFMA16(a, b, O[v]);
        }
      }
    }
  }

  // ---- final denominator: one cross-lane reduce ----
  #pragma unroll
  for (int r = 0; r < 4; ++r) {
    #pragma unroll
    for (int m = 1; m < 16; m <<= 1) rl[r] += __shfl_xor(rl[r], m);
  }

  // ---- retrieved -> LDS fp16 (P dead -> ret) ----
  #pragma unroll
  for (int v = 0; v < 8; ++v)
    #pragma unroll
    for (int r = 0; r < 4; ++r)
      P_s[(quad * 4 + r) * 136 + v * 16 + l15] = (_Float16)(O[v][r] / rl[r]);

  // contiguous nt stores: 8 iters x (64 lanes x 16 B) = full lines
  #pragma unroll
  for (int it = 0; it < 8; ++it) {
    int flat = it * 256 + lane * 4;            // element within 16x128 tile
    int row = flat >> 7, col = flat & 127;
    h4v t = *(const h4v*)&P_s[row * 136 + col];
    f4v o;
    o.x = (float)t[0]; o.y = (float)t[1]; o.z = (float)t[2]; o.w = (float)t[3];
    __builtin_nontemporal_store(o, (f4v*)(out_ret + (size_t)q0 * VAL + flat));
  }

  // ---- c1: relu([qf|ret] @ c1_W + b); h1 overwrites ret in place ----
  h8v qf0 = __builtin_nontemporal_load((const h8v*)(qfpq + fb + 0 * 512 + lane * 8));
  h8v qf1 = __builtin_nontemporal_load((const h8v*)(qfpq + fb + 1 * 512 + lane * 8));
  {
    f4v H[8];
    #pragma unroll
    for (int f = 0; f < 8; ++f) H[f] = fz;
    #pragma unroll
    for (int ks = 0; ks < 6; ++ks) {
      const int k0 = ks * 32;
      h8v a = (ks == 0) ? qf0 : (ks == 1) ? qf1
               : *(const h8v*)&P_s[l15 * 136 + (k0 - 64) + quad * 8];
      #pragma unroll
      for (int f = 0; f < 8; ++f) {
        h8v b = *(const h8v*)(c1F + (size_t)(f * 6 + ks) * 512 + lane * 8);
        H[f] = MFMA16(a, b, H[f]);
      }
    }
    #pragma unroll
    for (int f = 0; f < 8; ++f) {
      float bb = c1_b[f * 16 + l15];
      #pragma unroll
      for (int r = 0; r < 4; ++r)
        P_s[(quad * 4 + r) * 136 + f * 16 + l15] =
            (_Float16)fmaxf(0.f, H[f][r] + bb);
    }
  }

  // ---- c2: relu(h1 @ c2_W + b) -> h2 ----
  {
    f4v G[4];
    #pragma unroll
    for (int f = 0; f < 4; ++f) G[f] = fz;
    #pragma unroll
    for (int ks = 0; ks < 4; ++ks) {
      h8v a = *(const h8v*)&P_s[l15 * 136 + ks * 32 + quad * 8];
      #pragma unroll
      for (int f = 0; f < 4; ++f) {
        h8v b = *(const h8v*)(c2F + (size_t)(f * 4 + ks) * 512 + lane * 8);
        G[f] = MFMA16(a, b, G[f]);
      }
    }
    #pragma unroll
    for (int f = 0; f < 4; ++f) {
      float bb = c2_b[f * 16 + l15];
      #pragma unroll
      for (int r = 0; r < 4; ++r)
        h2_s[(quad * 4 + r) * 72 + f * 16 + l15] =
            (_Float16)fmaxf(0.f, G[f][r] + bb);
    }
  }

  // ---- c3 + loss (4 lanes per query row) ----
  float lsum;
  {
    const int prow = lane >> 2, pj = lane & 3;
    float s = 0.f;
    #pragma unroll
    for (int k = 0; k < 16; ++k) {
      int kk = pj * 16 + k;
      s += (float)h2_s[prow * 72 + kk] * c3W[kk];
    }
    s += __shfl_xor(s, 1);
    s += __shfl_xor(s, 2);
    float pred = s + c3b[0];
    float diff = pred - qy[q0 + prow];
    if (pj == 0) out_pred[q0 + prow] = pred;
    lsum = diff * diff;                        // each row counted 4x
  }
  #pragma unroll
  for (int m = 1; m < 64; m <<= 1) lsum += __shfl_xor(lsum, m);
  if (lane == 0) atomicAdd(dout, lsum * (1.0f / (4.0f * (float)BQ)));
}

// ---------------------------------------------------------------------------
extern "C" void kernel_launch(void* const* d_in, const int* in_sizes, int n_in,
                              void* d_out, int out_size, void* d_ws, size_t ws_size,
                              hipStream_t stream)
{
  const float* support_x = (const float*)d_in[0];
  const float* support_y = (const float*)d_in[1];
  const float* query_x   = (const float*)d_in[2];
  const float* query_y   = (const float*)d_in[3];
  const float* base_W    = (const float*)d_in[4];
  const float* base_b    = (const float*)d_in[5];
  const float* kp_W      = (const float*)d_in[6];
  const float* kp_b      = (const float*)d_in[7];
  const float* vp_W      = (const float*)d_in[8];
  const float* vp_b      = (const float*)d_in[9];
  const float* mem_keys  = (const float*)d_in[10];
  const float* mem_vals  = (const float*)d_in[11];
  const float* mem_age   = (const float*)d_in[12];
  const float* c1_W      = (const float*)d_in[13];
  const float* c1_b      = (const float*)d_in[14];
  const float* c2_W      = (const float*)d_in[15];
  const float* c2_b      = (const float*)d_in[16];
  const float* c3_W      = (const float*)d_in[17];
  const float* c3_b      = (const float*)d_in[18];

  char* w = (char*)d_ws;                        // ~17.8 MB used
  _Float16* WTf   = (_Float16*)(w + 0);         // 128 KB fragment-major
  _Float16* vpWt  = (_Float16*)(w + 131072);    // 32 KB
  _Float16* c1F   = (_Float16*)(w + 163840);    // 48 KB fragment-major
  _Float16* c2F   = (_Float16*)(w + 212992);    // 16 KB fragment-major
  float*    bcomb = (float*)   (w + 229376);    // 512 B
  int*      ranks = (int*)     (w + 229888);    // 4 KB
  float*    pkeys = (float*)   (w + 233984);    // 128 KB
  float*    pvals = (float*)   (w + 365056);    // 256 KB
  _Float16* keysF = (_Float16*)(w + 627200);    // 128 KB fragment-major
  _Float16* valF  = (_Float16*)(w + 758272);    // 256 KB fragment-major
  _Float16* qfpq  = (_Float16*)(w + 1048576);   // 16 MB A-frag-major

  float* out = (float*)d_out;

  hipLaunchKernelGGL(k_prep1, dim3(453), dim3(256), 0, stream,
                     base_W, base_b, kp_W, kp_b, vp_W, c1_W, c2_W, mem_age,
                     WTf, bcomb, vpWt, c1F, c2F, ranks, out);
  hipLaunchKernelGGL(k_prep2, dim3(64), dim3(64), 0, stream,
                     support_x, support_y, WTf, bcomb, vpWt, vp_b, pkeys, pvals);
  hipLaunchKernelGGL(k_prep3, dim3(768), dim3(256), 0, stream,
                     ranks, pkeys, pvals, mem_keys, mem_vals, keysF, valF);
  hipLaunchKernelGGL(k_feat, dim3(BQ / 16), dim3(64), 0, stream,
                     query_x, WTf, bcomb, qfpq);
  hipLaunchKernelGGL(k_main, dim3(BQ / 16), dim3(64), 0, stream,
                     qfpq, query_y, c1_b, c2_b, c3_W, c3_b,
                     c1F, c2F, keysF, valF, out);
}

// Round 2
// 404.884 us; speedup vs baseline: 1.1887x; 1.1576x over previous
//
#include <hip/hip_runtime.h>

typedef _Float16 h8v __attribute__((ext_vector_type(8)));
typedef _Float16 h4v __attribute__((ext_vector_type(4)));
typedef float    f4v __attribute__((ext_vector_type(4)));

#define MFMA16(a,b,c) __builtin_amdgcn_mfma_f32_16x16x32_f16((a),(b),(c),0,0,0)
#define NEGF (-1e30f)

#define MEM 1000
#define KEY 64
#define VAL 128
#define DIN 512
#define BS  512
#define BQ  65536

// Fragment-major B layouts: element (F,KS,lane,j) at ((F*nKS+KS)*64+lane)*8+j
// holds B[n = F*16 + (lane&15)][k = KS*32 + (lane>>4)*8 + j]  -> every MFMA
// B-fragment load is lane-contiguous (16 B/lane, 1 KB/wave, 8 full lines),
// and (critically for global_load_lds) LINEAR: LDS dest = uniform base +
// lane*16 B matches the fragment layout exactly.
// qfpq is A-fragment-major: tile t (16 queries), frag KS in 0..3 (k=KS*32..):
// offset ((t*4+KS)*64+lane)*8 ; KS 0,1 = qf cols, KS 2,3 = pq cols.

typedef __attribute__((address_space(1))) const unsigned int guint;
typedef __attribute__((address_space(3))) unsigned int luint;

// async global->LDS, 16 B/lane: LDS gets [uniform l + lane*16B] = g[lane*16B]
__device__ __forceinline__ void gld16(const _Float16* g, _Float16* l)
{
  __builtin_amdgcn_global_load_lds((guint*)g, (luint*)l, 16, 0, 0);
}

__device__ __forceinline__ h8v cvt8(const float* p)
{
  f4v u = *(const f4v*)p;
  f4v v = *(const f4v*)(p + 4);
  h8v a;
  a[0] = (_Float16)u.x; a[1] = (_Float16)u.y; a[2] = (_Float16)u.z; a[3] = (_Float16)u.w;
  a[4] = (_Float16)v.x; a[5] = (_Float16)v.y; a[6] = (_Float16)v.z; a[7] = (_Float16)v.w;
  return a;
}

__device__ __forceinline__ h8v cvt8nt(const float* p)
{
  f4v u = __builtin_nontemporal_load((const f4v*)p);
  f4v v = __builtin_nontemporal_load((const f4v*)(p + 4));
  h8v a;
  a[0] = (_Float16)u.x; a[1] = (_Float16)u.y; a[2] = (_Float16)u.z; a[3] = (_Float16)u.w;
  a[4] = (_Float16)v.x; a[5] = (_Float16)v.y; a[6] = (_Float16)v.z; a[7] = (_Float16)v.w;
  return a;
}

// ---------------------------------------------------------------------------
// prep1: fragment-major weights, Wck = baseW@kpW fused, bcomb, ranks, zero
// ---------------------------------------------------------------------------
__global__ void k_prep1(const float* __restrict__ baseW, const float* __restrict__ base_b,
                        const float* __restrict__ kpW, const float* __restrict__ kp_b,
                        const float* __restrict__ vpW, const float* __restrict__ c1W,
                        const float* __restrict__ c2W, const float* __restrict__ age,
                        _Float16* __restrict__ WTf, float* __restrict__ bcomb,
                        _Float16* __restrict__ vpWt, _Float16* __restrict__ c1F,
                        _Float16* __restrict__ c2F, int* __restrict__ ranks,
                        float* __restrict__ out0)
{
  long id = (long)blockIdx.x * 256 + threadIdx.x;
  if (id < 65536) {                        // WTf: [baseW^T | Wck^T], n=128, k=512 (KS=16)
    int h = (int)id;
    int j = h & 7, lane = (h >> 3) & 63, KS = (h >> 9) & 15, F = h >> 13;
    int n = F * 16 + (lane & 15);
    int k = KS * 32 + ((lane >> 4) << 3) + j;
    float v;
    if (n < 64) v = baseW[(size_t)k * 64 + n];
    else {
      int nn = n - 64;
      const float* br = baseW + (size_t)k * 64;
      float s = 0.f;
      for (int t = 0; t < 64; ++t) s += br[t] * kpW[t * 64 + nn];
      v = s;
    }
    WTf[h] = (_Float16)v;
  } else if (id < 65664) {                 // bcomb
    int i = (int)(id - 65536);
    if (i < 64) bcomb[i] = base_b[i];
    else {
      int n = i - 64;
      float s = kp_b[n];
      for (int t = 0; t < 64; ++t) s += base_b[t] * kpW[t * 64 + n];
      bcomb[i] = s;
    }
  } else if (id < 90240) {                 // c1F: n=128 (F=8), k=192 (KS=6)
    int h = (int)(id - 65664);
    int j = h & 7, lane = (h >> 3) & 63, KS = (h >> 9) % 6, F = (h >> 9) / 6;
    int n = F * 16 + (lane & 15);
    int k = KS * 32 + ((lane >> 4) << 3) + j;
    c1F[h] = (_Float16)c1W[(size_t)k * 128 + n];
  } else if (id < 98432) {                 // c2F: n=64 (F=4), k=128 (KS=4)
    int h = (int)(id - 90240);
    int j = h & 7, lane = (h >> 3) & 63, KS = (h >> 9) & 3, F = h >> 11;
    int n = F * 16 + (lane & 15);
    int k = KS * 32 + ((lane >> 4) << 3) + j;
    c2F[h] = (_Float16)c2W[(size_t)k * 64 + n];
  } else if (id < 114816) {                // vpWt[n][k] (row-major transposed, prep2 only)
    long i = id - 98432;
    int n = (int)(i >> 7), k = (int)(i & 127);
    vpWt[i] = (_Float16)vpW[(size_t)k * 128 + n];
  } else if (id < 115816) {                // stable ranks (lax.top_k order)
    int jx = (int)(id - 114816);
    float aj = age[jx];
    int r = 0;
    for (int i2 = 0; i2 < MEM; ++i2) {
      float ai = age[i2];
      r += (ai > aj) || (ai == aj && i2 < jx);
    }
    ranks[jx] = r;
  } else if (id == 115816) {
    *out0 = 0.f;
  }
}

// ---------------------------------------------------------------------------
// prep2: pkeys = sx@Wck + bck ; pvals = sy@vpW + vp_b
// ---------------------------------------------------------------------------
__global__ __launch_bounds__(64) void k_prep2(
    const float* __restrict__ sx, const float* __restrict__ sy,
    const _Float16* __restrict__ WTf, const float* __restrict__ bcomb,
    const _Float16* __restrict__ vpWt, const float* __restrict__ vp_b,
    float* __restrict__ pkeys, float* __restrict__ pvals)
{
  const int lane = threadIdx.x, quad = lane >> 4, l15 = lane & 15;
  const f4v fz = {0.f, 0.f, 0.f, 0.f};
  if (blockIdx.x < 32) {
    const int m0 = blockIdx.x * 16;
    f4v acc[4];
    #pragma unroll
    for (int f = 0; f < 4; ++f) acc[f] = fz;
    const float* xr = sx + (size_t)(m0 + l15) * DIN;
    #pragma unroll 4
    for (int ks = 0; ks < 16; ++ks) {
      int k0 = ks * 32 + quad * 8;
      h8v a = cvt8(xr + k0);
      #pragma unroll
      for (int f = 0; f < 4; ++f) {
        h8v b = *(const h8v*)(WTf + (size_t)((((4 + f) * 16) + ks) * 64 + lane) * 8);
        acc[f] = MFMA16(a, b, acc[f]);
      }
    }
    #pragma unroll
    for (int f = 0; f < 4; ++f) {
      int col = f * 16 + l15;
      float bb = bcomb[64 + col];
      #pragma unroll
      for (int r = 0; r < 4; ++r)
        pkeys[(size_t)(m0 + quad * 4 + r) * KEY + col] = acc[f][r] + bb;
    }
  } else {
    const int m0 = (blockIdx.x - 32) * 16;
    f4v acc[8];
    #pragma unroll
    for (int f = 0; f < 8; ++f) acc[f] = fz;
    const float* yr = sy + (size_t)(m0 + l15) * VAL;
    #pragma unroll
    for (int ks = 0; ks < 4; ++ks) {
      int k0 = ks * 32 + quad * 8;
      h8v a = cvt8(yr + k0);
      #pragma unroll
      for (int f = 0; f < 8; ++f) {
        h8v b = *(const h8v*)(vpWt + (size_t)(f * 16 + l15) * 128 + k0);
        acc[f] = MFMA16(a, b, acc[f]);
      }
    }
    #pragma unroll
    for (int f = 0; f < 8; ++f) {
      int col = f * 16 + l15;
      float bb = vp_b[col];
      #pragma unroll
      for (int r = 0; r < 4; ++r)
        pvals[(size_t)(m0 + quad * 4 + r) * VAL + col] = acc[f][r] + bb;
    }
  }
}

// ---------------------------------------------------------------------------
// prep3: scatter memory into fragment-major keysF / valF (zero-padded)
// keysF: n=1024 slots (F=64), k=KEY 64 (KS=2)
// valF : n=VAL 128 (F=8),     k=1024 slots (KS=32)
// ---------------------------------------------------------------------------
__global__ void k_prep3(const int* __restrict__ ranks, const float* __restrict__ pk,
                        const float* __restrict__ pv, const float* __restrict__ memK,
                        const float* __restrict__ memV,
                        _Float16* __restrict__ keysF, _Float16* __restrict__ valF)
{
  int id = blockIdx.x * 256 + threadIdx.x;
  if (id < 65536) {
    int j = id & 7, lane = (id >> 3) & 63, KS = (id >> 9) & 1, F = id >> 10;
    int n = F * 16 + (lane & 15);                  // mem slot
    int k = KS * 32 + ((lane >> 4) << 3) + j;      // key col
    float v = 0.f;
    if (n < MEM) {
      int rk = ranks[n];
      v = (rk < BS) ? pk[(size_t)rk * KEY + k] : memK[(size_t)n * KEY + k];
    }
    keysF[id] = (_Float16)v;
  } else {
    int h = id - 65536;
    int j = h & 7, lane = (h >> 3) & 63, KS = (h >> 9) & 31, F = h >> 14;
    int nv = F * 16 + (lane & 15);                 // val col
    int jm = KS * 32 + ((lane >> 4) << 3) + j;     // mem slot
    float v = 0.f;
    if (jm < MEM) {
      int rk = ranks[jm];
      v = (rk < BS) ? pv[(size_t)rk * VAL + nv] : memV[(size_t)jm * VAL + nv];
    }
    valF[h] = (_Float16)v;
  }
}

// ---------------------------------------------------------------------------
// feat: qfpq (A-frag-major) = qx @ [baseW | Wck] + bcomb.
// 4 waves/block, 64 queries/block, grid 1024. WTf (128 KB, read by every
// wave) is staged ONCE per block into LDS via global_load_lds; b-fragments
// then come from LDS (~12 cyc ds_read_b128) instead of ~270 cyc L2 hops.
// Round-1 rocprof: k_main-style global b-fragment chains left MfmaUtil at
// 6% and the wave ~85% stalled on vmcnt; same pathology here.
// ---------------------------------------------------------------------------
__global__ __launch_bounds__(256) void k_feat(const float* __restrict__ qx,
                                              const _Float16* __restrict__ WTf,
                                              const float* __restrict__ bcomb,
                                              _Float16* __restrict__ qfpq)
{
  __shared__ __align__(16) _Float16 WTsh[65536];    // 128 KB
  __shared__ __align__(16) _Float16 tb[4][2176];    // 17 KB (per-wave transpose)

  const int tid = threadIdx.x, wid = tid >> 6, lane = tid & 63;
  const int quad = lane >> 4, l15 = lane & 15;

  // stage all of WTf: 128 tiles x 1 KB, 32 per wave
  #pragma unroll
  for (int i = 0; i < 32; ++i) {
    const int t = wid * 32 + i;
    gld16(WTf + (size_t)t * 512 + lane * 8, WTsh + t * 512);
  }
  asm volatile("s_waitcnt vmcnt(0)" ::: "memory");
  __syncthreads();

  const int tile = blockIdx.x * 4 + wid;
  const int q0 = tile * 16;
  const f4v fz = {0.f, 0.f, 0.f, 0.f};
  f4v acc[8];
  #pragma unroll
  for (int f = 0; f < 8; ++f) acc[f] = fz;

  const float* xr = qx + (size_t)(q0 + l15) * DIN;

  #pragma unroll 4
  for (int ks = 0; ks < 16; ++ks) {
    const int k0 = ks * 32 + quad * 8;
    h8v a = cvt8nt(xr + k0);
    #pragma unroll
    for (int f = 0; f < 8; ++f) {
      h8v b = *(const h8v*)(WTsh + (size_t)((f * 16 + ks) * 64 + lane) * 8);
      acc[f] = MFMA16(a, b, acc[f]);
    }
  }
  // C-layout -> LDS -> A-frag-major contiguous nt stores
  _Float16* tbuf = tb[wid];
  #pragma unroll
  for (int f = 0; f < 8; ++f) {
    float bb = bcomb[f * 16 + l15];
    #pragma unroll
    for (int r = 0; r < 4; ++r)
      tbuf[(quad * 4 + r) * 136 + f * 16 + l15] = (_Float16)(acc[f][r] + bb);
  }
  const size_t ob = (size_t)tile * 4 * 512;
  #pragma unroll
  for (int KS = 0; KS < 4; ++KS) {
    h8v v = *(const h8v*)&tbuf[l15 * 136 + KS * 32 + quad * 8];
    __builtin_nontemporal_store(v, (h8v*)(qfpq + ob + KS * 512 + lane * 8));
  }
}

// ---------------------------------------------------------------------------
// main: fused attention + controller. 4 waves/block (16 queries each),
// grid 1024. keysF/valF are staged chunk-by-chunk (128 mem slots: 16 KB K +
// 32 KB V) into double-buffered LDS shared by all 4 waves; stage of chunk
// c+1 is issued before compute of chunk c (T3 2-phase) so L2 latency hides
// under MFMA+softmax. LDS 125 KB -> 1 block/CU; that's fine because the
// critical path is now LDS-latency, not global-latency.
// ---------------------------------------------------------------------------
__global__ __launch_bounds__(256) void k_main(
    const _Float16* __restrict__ qfpq, const float* __restrict__ qy,
    const float* __restrict__ c1_b, const float* __restrict__ c2_b,
    const float* __restrict__ c3W, const float* __restrict__ c3b,
    const _Float16* __restrict__ c1F, const _Float16* __restrict__ c2F,
    const _Float16* __restrict__ keysF, const _Float16* __restrict__ valF,
    float* __restrict__ dout)
{
  __shared__ __align__(16) _Float16 Ksh[2][8192];    // 2 x 16 KB
  __shared__ __align__(16) _Float16 Vsh[2][16384];   // 2 x 32 KB
  __shared__ __align__(16) _Float16 Pwk[4][3328];    // per-wave P(2176)+h2(1152)

  const int tid  = threadIdx.x;
  const int wid  = tid >> 6;
  const int lane = tid & 63;
  const int quad = lane >> 4;
  const int l15  = lane & 15;
  const int tile = blockIdx.x * 4 + wid;
  const int q0   = tile * 16;

  _Float16* P_s  = Pwk[wid];
  _Float16* h2_s = Pwk[wid] + 2176;

  float* out_pred = dout + 1;
  float* out_ret  = dout + 1 + BQ;
  const f4v fz = {0.f, 0.f, 0.f, 0.f};

  // ---- stage chunk 0 (all 4 waves cooperate: 4 K-tiles + 8 V-tiles each) --
  {
    const _Float16* kc = keysF;            // chunk 0
    #pragma unroll
    for (int i = 0; i < 4; ++i) {
      const int t = wid * 4 + i;
      gld16(kc + (size_t)t * 512 + lane * 8, Ksh[0] + t * 512);
    }
    #pragma unroll
    for (int i = 0; i < 8; ++i) {
      const int t = wid * 8 + i;
      const int v = t >> 2, sub = t & 3;
      gld16(valF + ((size_t)(v * 32 + 0 * 4 + sub)) * 512 + lane * 8,
            Vsh[0] + (v * 4 + sub) * 512);
    }
  }

  const size_t fb = (size_t)tile * 4 * 512;  // A-frag base (halves)
  h8v pq0 = __builtin_nontemporal_load((const h8v*)(qfpq + fb + 2 * 512 + lane * 8));
  h8v pq1 = __builtin_nontemporal_load((const h8v*)(qfpq + fb + 3 * 512 + lane * 8));

  asm volatile("s_waitcnt vmcnt(0)" ::: "memory");
  __syncthreads();

  // ---- attention: online softmax over 8 chunks of 128 slots ----
  float rm[4], rl[4];
  #pragma unroll
  for (int r = 0; r < 4; ++r) { rm[r] = NEGF; rl[r] = 0.f; }
  f4v O[8];
  #pragma unroll
  for (int v = 0; v < 8; ++v) O[v] = fz;

  #pragma unroll 1
  for (int c = 0; c < 8; ++c) {
    const int cur = c & 1;

    // issue next chunk's staging first (latency hides under compute below)
    if (c < 7) {
      const int nc = c + 1;
      const _Float16* kc = keysF + (size_t)nc * 8192;
      #pragma unroll
      for (int i = 0; i < 4; ++i) {
        const int t = wid * 4 + i;
        gld16(kc + (size_t)t * 512 + lane * 8, Ksh[cur ^ 1] + t * 512);
      }
      #pragma unroll
      for (int i = 0; i < 8; ++i) {
        const int t = wid * 8 + i;
        const int v = t >> 2, sub = t & 3;
        gld16(valF + ((size_t)(v * 32 + nc * 4 + sub)) * 512 + lane * 8,
              Vsh[cur ^ 1] + (v * 4 + sub) * 512);
      }
    }

    // ---- QK^T for this chunk (b-fragments from LDS) ----
    f4v S[8];
    #pragma unroll
    for (int f = 0; f < 8; ++f) S[f] = fz;
    const _Float16* Kb = Ksh[cur];
    #pragma unroll
    for (int f = 0; f < 8; ++f) {
      h8v b0 = *(const h8v*)(Kb + (size_t)(f * 2 + 0) * 512 + lane * 8);
      h8v b1 = *(const h8v*)(Kb + (size_t)(f * 2 + 1) * 512 + lane * 8);
      S[f] = MFMA16(pq0, b0, S[f]);
      S[f] = MFMA16(pq1, b1, S[f]);
    }

    // ---- online softmax (identical math/order to previous version) ----
    float cm[4] = {NEGF, NEGF, NEGF, NEGF};
    #pragma unroll
    for (int f = 0; f < 8; ++f) {
      const int col = c * 128 + f * 16 + l15;
      const bool ok = (col < MEM);
      #pragma unroll
      for (int r = 0; r < 4; ++r) {
        float s = ok ? S[f][r] : NEGF;
        S[f][r] = s;
        cm[r] = fmaxf(cm[r], s);
      }
    }
    #pragma unroll
    for (int r = 0; r < 4; ++r) {
      #pragma unroll
      for (int m = 1; m < 16; m <<= 1) cm[r] = fmaxf(cm[r], __shfl_xor(cm[r], m));
    }
    float al[4];
    #pragma unroll
    for (int r = 0; r < 4; ++r) {
      float mn = fmaxf(rm[r], cm[r]);
      al[r] = __expf(rm[r] - mn);
      rm[r] = mn;
    }
    float psl[4] = {0.f, 0.f, 0.f, 0.f};       // per-lane partial sum
    #pragma unroll
    for (int f = 0; f < 8; ++f)
      #pragma unroll
      for (int r = 0; r < 4; ++r) {
        float p = __expf(S[f][r] - rm[r]);
        S[f][r] = p;
        psl[r] += p;
      }
    #pragma unroll
    for (int r = 0; r < 4; ++r) rl[r] = rl[r] * al[r] + psl[r];

    // ---- P -> LDS (C-layout -> A-layout), rescale O, P @ V ----
    #pragma unroll
    for (int f = 0; f < 8; ++f)
      #pragma unroll
      for (int r = 0; r < 4; ++r)
        P_s[(quad * 4 + r) * 136 + f * 16 + l15] = (_Float16)S[f][r];
    #pragma unroll
    for (int v = 0; v < 8; ++v)
      #pragma unroll
      for (int r = 0; r < 4; ++r) O[v][r] *= al[r];
    const _Float16* Vb = Vsh[cur];
    #pragma unroll
    for (int ks = 0; ks < 4; ++ks) {
      h8v a = *(const h8v*)&P_s[l15 * 136 + ks * 32 + quad * 8];
      #pragma unroll
      for (int v = 0; v < 8; ++v) {
        h8v b = *(const h8v*)(Vb + (size_t)(v * 4 + ks) * 512 + lane * 8);
        O[v] = MFMA16(a, b, O[v]);
      }
    }

    // drain next-chunk staging + protect buffer reuse across all 4 waves
    asm volatile("s_waitcnt vmcnt(0)" ::: "memory");
    __syncthreads();
  }

  // ---- final denominator: one cross-lane reduce ----
  #pragma unroll
  for (int r = 0; r < 4; ++r) {
    #pragma unroll
    for (int m = 1; m < 16; m <<= 1) rl[r] += __shfl_xor(rl[r], m);
  }

  // ---- retrieved -> LDS fp16 (P dead -> ret) ----
  #pragma unroll
  for (int v = 0; v < 8; ++v)
    #pragma unroll
    for (int r = 0; r < 4; ++r)
      P_s[(quad * 4 + r) * 136 + v * 16 + l15] = (_Float16)(O[v][r] / rl[r]);

  // contiguous nt stores: 8 iters x (64 lanes x 16 B) = full lines
  #pragma unroll
  for (int it = 0; it < 8; ++it) {
    int flat = it * 256 + lane * 4;            // element within 16x128 tile
    int row = flat >> 7, col = flat & 127;
    h4v t = *(const h4v*)&P_s[row * 136 + col];
    f4v o;
    o.x = (float)t[0]; o.y = (float)t[1]; o.z = (float)t[2]; o.w = (float)t[3];
    __builtin_nontemporal_store(o, (f4v*)(out_ret + (size_t)q0 * VAL + flat));
  }

  // ---- c1: relu([qf|ret] @ c1_W + b); h1 overwrites ret in place ----
  h8v qf0 = __builtin_nontemporal_load((const h8v*)(qfpq + fb + 0 * 512 + lane * 8));
  h8v qf1 = __builtin_nontemporal_load((const h8v*)(qfpq + fb + 1 * 512 + lane * 8));
  {
    f4v H[8];
    #pragma unroll
    for (int f = 0; f < 8; ++f) H[f] = fz;
    #pragma unroll
    for (int ks = 0; ks < 6; ++ks) {
      const int k0 = ks * 32;
      h8v a = (ks == 0) ? qf0 : (ks == 1) ? qf1
               : *(const h8v*)&P_s[l15 * 136 + (k0 - 64) + quad * 8];
      #pragma unroll
      for (int f = 0; f < 8; ++f) {
        h8v b = *(const h8v*)(c1F + (size_t)(f * 6 + ks) * 512 + lane * 8);
        H[f] = MFMA16(a, b, H[f]);
      }
    }
    #pragma unroll
    for (int f = 0; f < 8; ++f) {
      float bb = c1_b[f * 16 + l15];
      #pragma unroll
      for (int r = 0; r < 4; ++r)
        P_s[(quad * 4 + r) * 136 + f * 16 + l15] =
            (_Float16)fmaxf(0.f, H[f][r] + bb);
    }
  }

  // ---- c2: relu(h1 @ c2_W + b) -> h2 ----
  {
    f4v G[4];
    #pragma unroll
    for (int f = 0; f < 4; ++f) G[f] = fz;
    #pragma unroll
    for (int ks = 0; ks < 4; ++ks) {
      h8v a = *(const h8v*)&P_s[l15 * 136 + ks * 32 + quad * 8];
      #pragma unroll
      for (int f = 0; f < 4; ++f) {
        h8v b = *(const h8v*)(c2F + (size_t)(f * 4 + ks) * 512 + lane * 8);
        G[f] = MFMA16(a, b, G[f]);
      }
    }
    #pragma unroll
    for (int f = 0; f < 4; ++f) {
      float bb = c2_b[f * 16 + l15];
      #pragma unroll
      for (int r = 0; r < 4; ++r)
        h2_s[(quad * 4 + r) * 72 + f * 16 + l15] =
            (_Float16)fmaxf(0.f, G[f][r] + bb);
    }
  }

  // ---- c3 + loss (4 lanes per query row) ----
  float lsum;
  {
    const int prow = lane >> 2, pj = lane & 3;
    float s = 0.f;
    #pragma unroll
    for (int k = 0; k < 16; ++k) {
      int kk = pj * 16 + k;
      s += (float)h2_s[prow * 72 + kk] * c3W[kk];
    }
    s += __shfl_xor(s, 1);
    s += __shfl_xor(s, 2);
    float pred = s + c3b[0];
    float diff = pred - qy[q0 + prow];
    if (pj == 0) out_pred[q0 + prow] = pred;
    lsum = diff * diff;                        // each row counted 4x
  }
  #pragma unroll
  for (int m = 1; m < 64; m <<= 1) lsum += __shfl_xor(lsum, m);
  if (lane == 0) atomicAdd(dout, lsum * (1.0f / (4.0f * (float)BQ)));
}

// ---------------------------------------------------------------------------
extern "C" void kernel_launch(void* const* d_in, const int* in_sizes, int n_in,
                              void* d_out, int out_size, void* d_ws, size_t ws_size,
                              hipStream_t stream)
{
  const float* support_x = (const float*)d_in[0];
  const float* support_y = (const float*)d_in[1];
  const float* query_x   = (const float*)d_in[2];
  const float* query_y   = (const float*)d_in[3];
  const float* base_W    = (const float*)d_in[4];
  const float* base_b    = (const float*)d_in[5];
  const float* kp_W      = (const float*)d_in[6];
  const float* kp_b      = (const float*)d_in[7];
  const float* vp_W      = (const float*)d_in[8];
  const float* vp_b      = (const float*)d_in[9];
  const float* mem_keys  = (const float*)d_in[10];
  const float* mem_vals  = (const float*)d_in[11];
  const float* mem_age   = (const float*)d_in[12];
  const float* c1_W      = (const float*)d_in[13];
  const float* c1_b      = (const float*)d_in[14];
  const float* c2_W      = (const float*)d_in[15];
  const float* c2_b      = (const float*)d_in[16];
  const float* c3_W      = (const float*)d_in[17];
  const float* c3_b      = (const float*)d_in[18];

  char* w = (char*)d_ws;                        // ~17.8 MB used
  _Float16* WTf   = (_Float16*)(w + 0);         // 128 KB fragment-major
  _Float16* vpWt  = (_Float16*)(w + 131072);    // 32 KB
  _Float16* c1F   = (_Float16*)(w + 163840);    // 48 KB fragment-major
  _Float16* c2F   = (_Float16*)(w + 212992);    // 16 KB fragment-major
  float*    bcomb = (float*)   (w + 229376);    // 512 B
  int*      ranks = (int*)     (w + 229888);    // 4 KB
  float*    pkeys = (float*)   (w + 233984);    // 128 KB
  float*    pvals = (float*)   (w + 365056);    // 256 KB
  _Float16* keysF = (_Float16*)(w + 627200);    // 128 KB fragment-major
  _Float16* valF  = (_Float16*)(w + 758272);    // 256 KB fragment-major
  _Float16* qfpq  = (_Float16*)(w + 1048576);   // 16 MB A-frag-major

  float* out = (float*)d_out;

  hipLaunchKernelGGL(k_prep1, dim3(453), dim3(256), 0, stream,
                     base_W, base_b, kp_W, kp_b, vp_W, c1_W, c2_W, mem_age,
                     WTf, bcomb, vpWt, c1F, c2F, ranks, out);
  hipLaunchKernelGGL(k_prep2, dim3(64), dim3(64), 0, stream,
                     support_x, support_y, WTf, bcomb, vpWt, vp_b, pkeys, pvals);
  hipLaunchKernelGGL(k_prep3, dim3(768), dim3(256), 0, stream,
                     ranks, pkeys, pvals, mem_keys, mem_vals, keysF, valF);
  hipLaunchKernelGGL(k_feat, dim3(BQ / 64), dim3(256), 0, stream,
                     query_x, WTf, bcomb, qfpq);
  hipLaunchKernelGGL(k_main, dim3(BQ / 64), dim3(256), 0, stream,
                     qfpq, query_y, c1_b, c2_b, c3_W, c3_b,
                     c1F, c2F, keysF, valF, out);
}

// Round 3
// 375.008 us; speedup vs baseline: 1.2834x; 1.0797x over previous
//
#include <hip/hip_runtime.h>

typedef _Float16 h8v __attribute__((ext_vector_type(8)));
typedef _Float16 h4v __attribute__((ext_vector_type(4)));
typedef float    f4v __attribute__((ext_vector_type(4)));

#define MFMA16(a,b,c) __builtin_amdgcn_mfma_f32_16x16x32_f16((a),(b),(c),0,0,0)
#define NEGF (-1e30f)

#define MEM 1000
#define KEY 64
#define VAL 128
#define DIN 512
#define BS  512
#define BQ  65536

// Fragment-major B layouts: element (F,KS,lane,j) at ((F*nKS+KS)*64+lane)*8+j
// holds B[n = F*16 + (lane&15)][k = KS*32 + (lane>>4)*8 + j]  -> every MFMA
// B-fragment load is lane-contiguous (16 B/lane, 1 KB/wave, 8 full lines),
// and (critically for global_load_lds) LINEAR: LDS dest = uniform base +
// lane*16 B matches the fragment layout exactly.
// qfpq is A-fragment-major: tile t (16 queries), frag KS in 0..3 (k=KS*32..):
// offset ((t*4+KS)*64+lane)*8 ; KS 0,1 = qf cols, KS 2,3 = pq cols.

typedef __attribute__((address_space(1))) const unsigned int guint;
typedef __attribute__((address_space(3))) unsigned int luint;

// async global->LDS, 16 B/lane: LDS gets [uniform l + lane*16B] = g[lane*16B]
__device__ __forceinline__ void gld16(const _Float16* g, _Float16* l)
{
  __builtin_amdgcn_global_load_lds((guint*)g, (luint*)l, 16, 0, 0);
}

__device__ __forceinline__ h8v cvt8(const float* p)
{
  f4v u = *(const f4v*)p;
  f4v v = *(const f4v*)(p + 4);
  h8v a;
  a[0] = (_Float16)u.x; a[1] = (_Float16)u.y; a[2] = (_Float16)u.z; a[3] = (_Float16)u.w;
  a[4] = (_Float16)v.x; a[5] = (_Float16)v.y; a[6] = (_Float16)v.z; a[7] = (_Float16)v.w;
  return a;
}

__device__ __forceinline__ h8v cvt8nt(const float* p)
{
  f4v u = __builtin_nontemporal_load((const f4v*)p);
  f4v v = __builtin_nontemporal_load((const f4v*)(p + 4));
  h8v a;
  a[0] = (_Float16)u.x; a[1] = (_Float16)u.y; a[2] = (_Float16)u.z; a[3] = (_Float16)u.w;
  a[4] = (_Float16)v.x; a[5] = (_Float16)v.y; a[6] = (_Float16)v.z; a[7] = (_Float16)v.w;
  return a;
}

// ---------------------------------------------------------------------------
// prep1: fragment-major weights, Wck = baseW@kpW fused, bcomb, ranks, zero
// ---------------------------------------------------------------------------
__global__ void k_prep1(const float* __restrict__ baseW, const float* __restrict__ base_b,
                        const float* __restrict__ kpW, const float* __restrict__ kp_b,
                        const float* __restrict__ vpW, const float* __restrict__ c1W,
                        const float* __restrict__ c2W, const float* __restrict__ age,
                        _Float16* __restrict__ WTf, float* __restrict__ bcomb,
                        _Float16* __restrict__ vpWt, _Float16* __restrict__ c1F,
                        _Float16* __restrict__ c2F, int* __restrict__ ranks,
                        float* __restrict__ out0)
{
  long id = (long)blockIdx.x * 256 + threadIdx.x;
  if (id < 65536) {                        // WTf: [baseW^T | Wck^T], n=128, k=512 (KS=16)
    int h = (int)id;
    int j = h & 7, lane = (h >> 3) & 63, KS = (h >> 9) & 15, F = h >> 13;
    int n = F * 16 + (lane & 15);
    int k = KS * 32 + ((lane >> 4) << 3) + j;
    float v;
    if (n < 64) v = baseW[(size_t)k * 64 + n];
    else {
      int nn = n - 64;
      const float* br = baseW + (size_t)k * 64;
      float s = 0.f;
      for (int t = 0; t < 64; ++t) s += br[t] * kpW[t * 64 + nn];
      v = s;
    }
    WTf[h] = (_Float16)v;
  } else if (id < 65664) {                 // bcomb
    int i = (int)(id - 65536);
    if (i < 64) bcomb[i] = base_b[i];
    else {
      int n = i - 64;
      float s = kp_b[n];
      for (int t = 0; t < 64; ++t) s += base_b[t] * kpW[t * 64 + n];
      bcomb[i] = s;
    }
  } else if (id < 90240) {                 // c1F: n=128 (F=8), k=192 (KS=6)
    int h = (int)(id - 65664);
    int j = h & 7, lane = (h >> 3) & 63, KS = (h >> 9) % 6, F = (h >> 9) / 6;
    int n = F * 16 + (lane & 15);
    int k = KS * 32 + ((lane >> 4) << 3) + j;
    c1F[h] = (_Float16)c1W[(size_t)k * 128 + n];
  } else if (id < 98432) {                 // c2F: n=64 (F=4), k=128 (KS=4)
    int h = (int)(id - 90240);
    int j = h & 7, lane = (h >> 3) & 63, KS = (h >> 9) & 3, F = h >> 11;
    int n = F * 16 + (lane & 15);
    int k = KS * 32 + ((lane >> 4) << 3) + j;
    c2F[h] = (_Float16)c2W[(size_t)k * 64 + n];
  } else if (id < 114816) {                // vpWt[n][k] (row-major transposed, prep2 only)
    long i = id - 98432;
    int n = (int)(i >> 7), k = (int)(i & 127);
    vpWt[i] = (_Float16)vpW[(size_t)k * 128 + n];
  } else if (id < 115816) {                // stable ranks (lax.top_k order)
    int jx = (int)(id - 114816);
    float aj = age[jx];
    int r = 0;
    for (int i2 = 0; i2 < MEM; ++i2) {
      float ai = age[i2];
      r += (ai > aj) || (ai == aj && i2 < jx);
    }
    ranks[jx] = r;
  } else if (id == 115816) {
    *out0 = 0.f;
  }
}

// ---------------------------------------------------------------------------
// prep2: pkeys = sx@Wck + bck ; pvals = sy@vpW + vp_b
// ---------------------------------------------------------------------------
__global__ __launch_bounds__(64) void k_prep2(
    const float* __restrict__ sx, const float* __restrict__ sy,
    const _Float16* __restrict__ WTf, const float* __restrict__ bcomb,
    const _Float16* __restrict__ vpWt, const float* __restrict__ vp_b,
    float* __restrict__ pkeys, float* __restrict__ pvals)
{
  const int lane = threadIdx.x, quad = lane >> 4, l15 = lane & 15;
  const f4v fz = {0.f, 0.f, 0.f, 0.f};
  if (blockIdx.x < 32) {
    const int m0 = blockIdx.x * 16;
    f4v acc[4];
    #pragma unroll
    for (int f = 0; f < 4; ++f) acc[f] = fz;
    const float* xr = sx + (size_t)(m0 + l15) * DIN;
    #pragma unroll 4
    for (int ks = 0; ks < 16; ++ks) {
      int k0 = ks * 32 + quad * 8;
      h8v a = cvt8(xr + k0);
      #pragma unroll
      for (int f = 0; f < 4; ++f) {
        h8v b = *(const h8v*)(WTf + (size_t)((((4 + f) * 16) + ks) * 64 + lane) * 8);
        acc[f] = MFMA16(a, b, acc[f]);
      }
    }
    #pragma unroll
    for (int f = 0; f < 4; ++f) {
      int col = f * 16 + l15;
      float bb = bcomb[64 + col];
      #pragma unroll
      for (int r = 0; r < 4; ++r)
        pkeys[(size_t)(m0 + quad * 4 + r) * KEY + col] = acc[f][r] + bb;
    }
  } else {
    const int m0 = (blockIdx.x - 32) * 16;
    f4v acc[8];
    #pragma unroll
    for (int f = 0; f < 8; ++f) acc[f] = fz;
    const float* yr = sy + (size_t)(m0 + l15) * VAL;
    #pragma unroll
    for (int ks = 0; ks < 4; ++ks) {
      int k0 = ks * 32 + quad * 8;
      h8v a = cvt8(yr + k0);
      #pragma unroll
      for (int f = 0; f < 8; ++f) {
        h8v b = *(const h8v*)(vpWt + (size_t)(f * 16 + l15) * 128 + k0);
        acc[f] = MFMA16(a, b, acc[f]);
      }
    }
    #pragma unroll
    for (int f = 0; f < 8; ++f) {
      int col = f * 16 + l15;
      float bb = vp_b[col];
      #pragma unroll
      for (int r = 0; r < 4; ++r)
        pvals[(size_t)(m0 + quad * 4 + r) * VAL + col] = acc[f][r] + bb;
    }
  }
}

// ---------------------------------------------------------------------------
// prep3: scatter memory into fragment-major keysF / valF (zero-padded)
// keysF: n=1024 slots (F=64), k=KEY 64 (KS=2)
// valF : n=VAL 128 (F=8),     k=1024 slots (KS=32)
// ---------------------------------------------------------------------------
__global__ void k_prep3(const int* __restrict__ ranks, const float* __restrict__ pk,
                        const float* __restrict__ pv, const float* __restrict__ memK,
                        const float* __restrict__ memV,
                        _Float16* __restrict__ keysF, _Float16* __restrict__ valF)
{
  int id = blockIdx.x * 256 + threadIdx.x;
  if (id < 65536) {
    int j = id & 7, lane = (id >> 3) & 63, KS = (id >> 9) & 1, F = id >> 10;
    int n = F * 16 + (lane & 15);                  // mem slot
    int k = KS * 32 + ((lane >> 4) << 3) + j;      // key col
    float v = 0.f;
    if (n < MEM) {
      int rk = ranks[n];
      v = (rk < BS) ? pk[(size_t)rk * KEY + k] : memK[(size_t)n * KEY + k];
    }
    keysF[id] = (_Float16)v;
  } else {
    int h = id - 65536;
    int j = h & 7, lane = (h >> 3) & 63, KS = (h >> 9) & 31, F = h >> 14;
    int nv = F * 16 + (lane & 15);                 // val col
    int jm = KS * 32 + ((lane >> 4) << 3) + j;     // mem slot
    float v = 0.f;
    if (jm < MEM) {
      int rk = ranks[jm];
      v = (rk < BS) ? pv[(size_t)rk * VAL + nv] : memV[(size_t)jm * VAL + nv];
    }
    valF[h] = (_Float16)v;
  }
}

// ---------------------------------------------------------------------------
// feat: qfpq (A-frag-major) = qx @ [baseW | Wck] + bcomb.
// 8 waves/block (512 thr), 128 queries/block, grid 512. WTsh (128 KB) staged
// once per block; after the MFMA loop a barrier lets us REUSE WTsh as the
// transpose buffer (saves 34 KB -> LDS 128 KB -> 2 waves/SIMD instead of 1;
// round-2 rocprof showed 1 wave/SIMD left all latencies exposed).
// ---------------------------------------------------------------------------
__global__ __launch_bounds__(512) void k_feat(const float* __restrict__ qx,
                                              const _Float16* __restrict__ WTf,
                                              const float* __restrict__ bcomb,
                                              _Float16* __restrict__ qfpq)
{
  __shared__ __align__(16) _Float16 WTsh[65536];    // 128 KB (reused as tb later)

  const int tid = threadIdx.x, wid = tid >> 6, lane = tid & 63;
  const int quad = lane >> 4, l15 = lane & 15;

  // stage all of WTf: 128 tiles x 1 KB, 16 per wave
  #pragma unroll
  for (int i = 0; i < 16; ++i) {
    const int t = wid * 16 + i;
    gld16(WTf + (size_t)t * 512 + lane * 8, WTsh + t * 512);
  }
  asm volatile("s_waitcnt vmcnt(0)" ::: "memory");
  __syncthreads();

  const int tile = blockIdx.x * 8 + wid;
  const int q0 = tile * 16;
  const f4v fz = {0.f, 0.f, 0.f, 0.f};
  f4v acc[8];
  #pragma unroll
  for (int f = 0; f < 8; ++f) acc[f] = fz;

  const float* xr = qx + (size_t)(q0 + l15) * DIN;

  #pragma unroll 4
  for (int ks = 0; ks < 16; ++ks) {
    const int k0 = ks * 32 + quad * 8;
    h8v a = cvt8nt(xr + k0);
    #pragma unroll
    for (int f = 0; f < 8; ++f) {
      h8v b = *(const h8v*)(WTsh + (size_t)((f * 16 + ks) * 64 + lane) * 8);
      acc[f] = MFMA16(a, b, acc[f]);
    }
  }

  // all waves done reading WTsh -> reuse it as per-wave transpose buffer
  __syncthreads();
  _Float16* tbuf = WTsh + wid * 2176;

  #pragma unroll
  for (int f = 0; f < 8; ++f) {
    float bb = bcomb[f * 16 + l15];
    #pragma unroll
    for (int r = 0; r < 4; ++r)
      tbuf[(quad * 4 + r) * 136 + f * 16 + l15] = (_Float16)(acc[f][r] + bb);
  }
  const size_t ob = (size_t)tile * 4 * 512;
  #pragma unroll
  for (int KS = 0; KS < 4; ++KS) {
    h8v v = *(const h8v*)&tbuf[l15 * 136 + KS * 32 + quad * 8];
    __builtin_nontemporal_store(v, (h8v*)(qfpq + ob + KS * 512 + lane * 8));
  }
}

// ---------------------------------------------------------------------------
// main: fused attention + controller. 8 waves/block (512 thr, 16 q each),
// grid 512. keysF/valF staged chunk-by-chunk (128 slots: 16 KB K + 32 KB V)
// into double-buffered LDS shared by all 8 waves; stage of chunk c+1 issued
// before compute of chunk c. LDS 148 KB -> 1 block/CU but 8 waves = 2/SIMD
// (round-2's 4-wave block gave 1 wave/SIMD: occupancy 10%, all latency
// exposed). Also halves K/V L2 re-read traffic (512 blocks x 384 KB).
// ---------------------------------------------------------------------------
__global__ __launch_bounds__(512) void k_main(
    const _Float16* __restrict__ qfpq, const float* __restrict__ qy,
    const float* __restrict__ c1_b, const float* __restrict__ c2_b,
    const float* __restrict__ c3W, const float* __restrict__ c3b,
    const _Float16* __restrict__ c1F, const _Float16* __restrict__ c2F,
    const _Float16* __restrict__ keysF, const _Float16* __restrict__ valF,
    float* __restrict__ dout)
{
  __shared__ __align__(16) _Float16 Ksh[2][8192];    // 2 x 16 KB
  __shared__ __align__(16) _Float16 Vsh[2][16384];   // 2 x 32 KB
  __shared__ __align__(16) _Float16 Pwk[8][3328];    // per-wave P(2176)+h2(1152)

  const int tid  = threadIdx.x;
  const int wid  = tid >> 6;
  const int lane = tid & 63;
  const int quad = lane >> 4;
  const int l15  = lane & 15;
  const int tile = blockIdx.x * 8 + wid;
  const int q0   = tile * 16;

  _Float16* P_s  = Pwk[wid];
  _Float16* h2_s = Pwk[wid] + 2176;

  float* out_pred = dout + 1;
  float* out_ret  = dout + 1 + BQ;
  const f4v fz = {0.f, 0.f, 0.f, 0.f};

  // ---- stage chunk 0 (8 waves cooperate: 2 K-tiles + 4 V-tiles each) ----
  {
    const _Float16* kc = keysF;            // chunk 0
    #pragma unroll
    for (int i = 0; i < 2; ++i) {
      const int t = wid * 2 + i;
      gld16(kc + (size_t)t * 512 + lane * 8, Ksh[0] + t * 512);
    }
    #pragma unroll
    for (int i = 0; i < 4; ++i) {
      const int t = wid * 4 + i;
      const int v = t >> 2, sub = t & 3;
      gld16(valF + ((size_t)(v * 32 + 0 * 4 + sub)) * 512 + lane * 8,
            Vsh[0] + (v * 4 + sub) * 512);
    }
  }

  const size_t fb = (size_t)tile * 4 * 512;  // A-frag base (halves)
  h8v pq0 = __builtin_nontemporal_load((const h8v*)(qfpq + fb + 2 * 512 + lane * 8));
  h8v pq1 = __builtin_nontemporal_load((const h8v*)(qfpq + fb + 3 * 512 + lane * 8));

  asm volatile("s_waitcnt vmcnt(0)" ::: "memory");
  __syncthreads();

  // ---- attention: online softmax over 8 chunks of 128 slots ----
  float rm[4], rl[4];
  #pragma unroll
  for (int r = 0; r < 4; ++r) { rm[r] = NEGF; rl[r] = 0.f; }
  f4v O[8];
  #pragma unroll
  for (int v = 0; v < 8; ++v) O[v] = fz;

  #pragma unroll 1
  for (int c = 0; c < 8; ++c) {
    const int cur = c & 1;

    // issue next chunk's staging first (latency hides under compute below)
    if (c < 7) {
      const int nc = c + 1;
      const _Float16* kc = keysF + (size_t)nc * 8192;
      #pragma unroll
      for (int i = 0; i < 2; ++i) {
        const int t = wid * 2 + i;
        gld16(kc + (size_t)t * 512 + lane * 8, Ksh[cur ^ 1] + t * 512);
      }
      #pragma unroll
      for (int i = 0; i < 4; ++i) {
        const int t = wid * 4 + i;
        const int v = t >> 2, sub = t & 3;
        gld16(valF + ((size_t)(v * 32 + nc * 4 + sub)) * 512 + lane * 8,
              Vsh[cur ^ 1] + (v * 4 + sub) * 512);
      }
    }

    // ---- QK^T for this chunk (b-fragments from LDS) ----
    f4v S[8];
    #pragma unroll
    for (int f = 0; f < 8; ++f) S[f] = fz;
    const _Float16* Kb = Ksh[cur];
    #pragma unroll
    for (int f = 0; f < 8; ++f) {
      h8v b0 = *(const h8v*)(Kb + (size_t)(f * 2 + 0) * 512 + lane * 8);
      h8v b1 = *(const h8v*)(Kb + (size_t)(f * 2 + 1) * 512 + lane * 8);
      S[f] = MFMA16(pq0, b0, S[f]);
      S[f] = MFMA16(pq1, b1, S[f]);
    }

    // ---- online softmax (identical math/order to previous version) ----
    float cm[4] = {NEGF, NEGF, NEGF, NEGF};
    #pragma unroll
    for (int f = 0; f < 8; ++f) {
      const int col = c * 128 + f * 16 + l15;
      const bool ok = (col < MEM);
      #pragma unroll
      for (int r = 0; r < 4; ++r) {
        float s = ok ? S[f][r] : NEGF;
        S[f][r] = s;
        cm[r] = fmaxf(cm[r], s);
      }
    }
    #pragma unroll
    for (int r = 0; r < 4; ++r) {
      #pragma unroll
      for (int m = 1; m < 16; m <<= 1) cm[r] = fmaxf(cm[r], __shfl_xor(cm[r], m));
    }
    float al[4];
    #pragma unroll
    for (int r = 0; r < 4; ++r) {
      float mn = fmaxf(rm[r], cm[r]);
      al[r] = __expf(rm[r] - mn);
      rm[r] = mn;
    }
    float psl[4] = {0.f, 0.f, 0.f, 0.f};       // per-lane partial sum
    #pragma unroll
    for (int f = 0; f < 8; ++f)
      #pragma unroll
      for (int r = 0; r < 4; ++r) {
        float p = __expf(S[f][r] - rm[r]);
        S[f][r] = p;
        psl[r] += p;
      }
    #pragma unroll
    for (int r = 0; r < 4; ++r) rl[r] = rl[r] * al[r] + psl[r];

    // ---- P -> LDS (C-layout -> A-layout), rescale O, P @ V ----
    #pragma unroll
    for (int f = 0; f < 8; ++f)
      #pragma unroll
      for (int r = 0; r < 4; ++r)
        P_s[(quad * 4 + r) * 136 + f * 16 + l15] = (_Float16)S[f][r];
    #pragma unroll
    for (int v = 0; v < 8; ++v)
      #pragma unroll
      for (int r = 0; r < 4; ++r) O[v][r] *= al[r];
    const _Float16* Vb = Vsh[cur];
    #pragma unroll
    for (int ks = 0; ks < 4; ++ks) {
      h8v a = *(const h8v*)&P_s[l15 * 136 + ks * 32 + quad * 8];
      #pragma unroll
      for (int v = 0; v < 8; ++v) {
        h8v b = *(const h8v*)(Vb + (size_t)(v * 4 + ks) * 512 + lane * 8);
        O[v] = MFMA16(a, b, O[v]);
      }
    }

    // drain next-chunk staging + protect buffer reuse across all 8 waves
    asm volatile("s_waitcnt vmcnt(0)" ::: "memory");
    __syncthreads();
  }

  // ---- final denominator: one cross-lane reduce ----
  #pragma unroll
  for (int r = 0; r < 4; ++r) {
    #pragma unroll
    for (int m = 1; m < 16; m <<= 1) rl[r] += __shfl_xor(rl[r], m);
  }

  // ---- retrieved -> LDS fp16 (P dead -> ret) ----
  #pragma unroll
  for (int v = 0; v < 8; ++v)
    #pragma unroll
    for (int r = 0; r < 4; ++r)
      P_s[(quad * 4 + r) * 136 + v * 16 + l15] = (_Float16)(O[v][r] / rl[r]);

  // contiguous nt stores: 8 iters x (64 lanes x 16 B) = full lines
  #pragma unroll
  for (int it = 0; it < 8; ++it) {
    int flat = it * 256 + lane * 4;            // element within 16x128 tile
    int row = flat >> 7, col = flat & 127;
    h4v t = *(const h4v*)&P_s[row * 136 + col];
    f4v o;
    o.x = (float)t[0]; o.y = (float)t[1]; o.z = (float)t[2]; o.w = (float)t[3];
    __builtin_nontemporal_store(o, (f4v*)(out_ret + (size_t)q0 * VAL + flat));
  }

  // ---- c1: relu([qf|ret] @ c1_W + b); h1 overwrites ret in place ----
  h8v qf0 = __builtin_nontemporal_load((const h8v*)(qfpq + fb + 0 * 512 + lane * 8));
  h8v qf1 = __builtin_nontemporal_load((const h8v*)(qfpq + fb + 1 * 512 + lane * 8));
  {
    f4v H[8];
    #pragma unroll
    for (int f = 0; f < 8; ++f) H[f] = fz;
    #pragma unroll
    for (int ks = 0; ks < 6; ++ks) {
      const int k0 = ks * 32;
      h8v a = (ks == 0) ? qf0 : (ks == 1) ? qf1
               : *(const h8v*)&P_s[l15 * 136 + (k0 - 64) + quad * 8];
      #pragma unroll
      for (int f = 0; f < 8; ++f) {
        h8v b = *(const h8v*)(c1F + (size_t)(f * 6 + ks) * 512 + lane * 8);
        H[f] = MFMA16(a, b, H[f]);
      }
    }
    #pragma unroll
    for (int f = 0; f < 8; ++f) {
      float bb = c1_b[f * 16 + l15];
      #pragma unroll
      for (int r = 0; r < 4; ++r)
        P_s[(quad * 4 + r) * 136 + f * 16 + l15] =
            (_Float16)fmaxf(0.f, H[f][r] + bb);
    }
  }

  // ---- c2: relu(h1 @ c2_W + b) -> h2 ----
  {
    f4v G[4];
    #pragma unroll
    for (int f = 0; f < 4; ++f) G[f] = fz;
    #pragma unroll
    for (int ks = 0; ks < 4; ++ks) {
      h8v a = *(const h8v*)&P_s[l15 * 136 + ks * 32 + quad * 8];
      #pragma unroll
      for (int f = 0; f < 4; ++f) {
        h8v b = *(const h8v*)(c2F + (size_t)(f * 4 + ks) * 512 + lane * 8);
        G[f] = MFMA16(a, b, G[f]);
      }
    }
    #pragma unroll
    for (int f = 0; f < 4; ++f) {
      float bb = c2_b[f * 16 + l15];
      #pragma unroll
      for (int r = 0; r < 4; ++r)
        h2_s[(quad * 4 + r) * 72 + f * 16 + l15] =
            (_Float16)fmaxf(0.f, G[f][r] + bb);
    }
  }

  // ---- c3 + loss (4 lanes per query row) ----
  float lsum;
  {
    const int prow = lane >> 2, pj = lane & 3;
    float s = 0.f;
    #pragma unroll
    for (int k = 0; k < 16; ++k) {
      int kk = pj * 16 + k;
      s += (float)h2_s[prow * 72 + kk] * c3W[kk];
    }
    s += __shfl_xor(s, 1);
    s += __shfl_xor(s, 2);
    float pred = s + c3b[0];
    float diff = pred - qy[q0 + prow];
    if (pj == 0) out_pred[q0 + prow] = pred;
    lsum = diff * diff;                        // each row counted 4x
  }
  #pragma unroll
  for (int m = 1; m < 64; m <<= 1) lsum += __shfl_xor(lsum, m);
  if (lane == 0) atomicAdd(dout, lsum * (1.0f / (4.0f * (float)BQ)));
}

// ---------------------------------------------------------------------------
extern "C" void kernel_launch(void* const* d_in, const int* in_sizes, int n_in,
                              void* d_out, int out_size, void* d_ws, size_t ws_size,
                              hipStream_t stream)
{
  const float* support_x = (const float*)d_in[0];
  const float* support_y = (const float*)d_in[1];
  const float* query_x   = (const float*)d_in[2];
  const float* query_y   = (const float*)d_in[3];
  const float* base_W    = (const float*)d_in[4];
  const float* base_b    = (const float*)d_in[5];
  const float* kp_W      = (const float*)d_in[6];
  const float* kp_b      = (const float*)d_in[7];
  const float* vp_W      = (const float*)d_in[8];
  const float* vp_b      = (const float*)d_in[9];
  const float* mem_keys  = (const float*)d_in[10];
  const float* mem_vals  = (const float*)d_in[11];
  const float* mem_age   = (const float*)d_in[12];
  const float* c1_W      = (const float*)d_in[13];
  const float* c1_b      = (const float*)d_in[14];
  const float* c2_W      = (const float*)d_in[15];
  const float* c2_b      = (const float*)d_in[16];
  const float* c3_W      = (const float*)d_in[17];
  const float* c3_b      = (const float*)d_in[18];

  char* w = (char*)d_ws;                        // ~17.8 MB used
  _Float16* WTf   = (_Float16*)(w + 0);         // 128 KB fragment-major
  _Float16* vpWt  = (_Float16*)(w + 131072);    // 32 KB
  _Float16* c1F   = (_Float16*)(w + 163840);    // 48 KB fragment-major
  _Float16* c2F   = (_Float16*)(w + 212992);    // 16 KB fragment-major
  float*    bcomb = (float*)   (w + 229376);    // 512 B
  int*      ranks = (int*)     (w + 229888);    // 4 KB
  float*    pkeys = (float*)   (w + 233984);    // 128 KB
  float*    pvals = (float*)   (w + 365056);    // 256 KB
  _Float16* keysF = (_Float16*)(w + 627200);    // 128 KB fragment-major
  _Float16* valF  = (_Float16*)(w + 758272);    // 256 KB fragment-major
  _Float16* qfpq  = (_Float16*)(w + 1048576);   // 16 MB A-frag-major

  float* out = (float*)d_out;

  hipLaunchKernelGGL(k_prep1, dim3(453), dim3(256), 0, stream,
                     base_W, base_b, kp_W, kp_b, vp_W, c1_W, c2_W, mem_age,
                     WTf, bcomb, vpWt, c1F, c2F, ranks, out);
  hipLaunchKernelGGL(k_prep2, dim3(64), dim3(64), 0, stream,
                     support_x, support_y, WTf, bcomb, vpWt, vp_b, pkeys, pvals);
  hipLaunchKernelGGL(k_prep3, dim3(768), dim3(256), 0, stream,
                     ranks, pkeys, pvals, mem_keys, mem_vals, keysF, valF);
  hipLaunchKernelGGL(k_feat, dim3(BQ / 128), dim3(512), 0, stream,
                     query_x, WTf, bcomb, qfpq);
  hipLaunchKernelGGL(k_main, dim3(BQ / 128), dim3(512), 0, stream,
                     qfpq, query_y, c1_b, c2_b, c3_W, c3_b,
                     c1F, c2F, keysF, valF, out);
}